// Round 8
// baseline (435.700 us; speedup 1.0000x reference)
//
#include <hip/hip_runtime.h>

// Problem constants (B=64, T=512, I=256, H=512)
#define BATCH 64
#define TSTEPS 512
#define IDIM 256
#define HDIM 512
#define MROWS (BATCH * TSTEPS)   // 32768

typedef __attribute__((address_space(1))) const void gvoid;
typedef __attribute__((address_space(3))) void lvoid;

__device__ __forceinline__ void gl2lds16(const void* g, void* l) {
    // async global->LDS, 16B per lane; LDS dest = wave-uniform base + lane*16
    __builtin_amdgcn_global_load_lds((gvoid*)g, (lvoid*)l, 16, 0, 0);
}

// ---------------------------------------------------------------------------
// K0: extract center taps: W1T[i][h] = conv1_w[h][i][1] ([k][n] layout);
//                          W2T[h][j] = conv2_w[j][h][1] ([k][n] layout)
// ---------------------------------------------------------------------------
__global__ void extract_weights(const float* __restrict__ c1w,
                                const float* __restrict__ c2w,
                                float* __restrict__ W1T,
                                float* __restrict__ W2T) {
    int tid = blockIdx.x * 256 + threadIdx.x;
    if (tid < IDIM * HDIM) {
        int i = tid >> 9;          // / 512
        int h = tid & 511;
        W1T[tid] = c1w[(h * IDIM + i) * 3 + 1];
    }
    if (tid < HDIM * HDIM) {
        int h = tid >> 9;
        int j = tid & 511;
        W2T[tid] = c2w[(j * HDIM + h) * 3 + 1];
    }
}

// ---------------------------------------------------------------------------
// G1 GEMM (round-4 shape, best measured for this role): BM=BN=128, BK=16,
// 256 threads, 8x8/thread. NUMERICS CONTRACT: one sequential k-ascending
// fp32 fmaf chain per output (bitwise identical to passing rounds).
// ---------------------------------------------------------------------------
#define BM1 128
#define BN1 128
#define BK1 16

__global__ __launch_bounds__(256, 2) void gemm_g1(const float* __restrict__ A,
                                                  const float* __restrict__ BT,
                                                  const float* __restrict__ bias,
                                                  float* __restrict__ C,
                                                  int K) {
    __shared__ __align__(16) float As[BK1 * BM1];   // [k][m]  8 KB
    __shared__ __align__(16) float Bs[BK1 * BN1];   // [k][n]  8 KB

    const int N = HDIM;
    int tid  = threadIdx.x;
    int lane = tid & 63;
    int wave = tid >> 6;
    int row0 = blockIdx.x * BM1;
    int col0 = blockIdx.y * BN1;
    int wm = (wave >> 1) * 64;
    int wn = (wave & 1) * 64;
    int mbase = wm + (lane >> 3) * 8;
    int nbase = wn + (lane & 7) * 8;

    float acc[8][8];
#pragma unroll
    for (int i = 0; i < 8; i++)
#pragma unroll
        for (int j = 0; j < 8; j++) acc[i][j] = 0.0f;

    int ar = tid >> 1;
    int ak = (tid & 1) * 8;
    const float* ap = A + (size_t)(row0 + ar) * K + ak;

    const char* bp = (const char*)(BT + (size_t)(tid >> 5) * N + col0) + (tid & 31) * 16;
    char* bld = (char*)Bs + tid * 16;
    const size_t bRow8 = (size_t)8 * N * sizeof(float);

    for (int k0 = 0; k0 < K; k0 += BK1) {
        gl2lds16(bp, bld);
        gl2lds16(bp + bRow8, bld + 4096);
        float4 a0 = *(const float4*)(ap);
        float4 a1 = *(const float4*)(ap + 4);
        ap += BK1;
        bp += (size_t)BK1 * N * sizeof(float);
        As[(ak + 0) * BM1 + ar] = a0.x;
        As[(ak + 1) * BM1 + ar] = a0.y;
        As[(ak + 2) * BM1 + ar] = a0.z;
        As[(ak + 3) * BM1 + ar] = a0.w;
        As[(ak + 4) * BM1 + ar] = a1.x;
        As[(ak + 5) * BM1 + ar] = a1.y;
        As[(ak + 6) * BM1 + ar] = a1.z;
        As[(ak + 7) * BM1 + ar] = a1.w;
        __syncthreads();

#pragma unroll
        for (int k = 0; k < BK1; k++) {
            float4 av0 = *(const float4*)&As[k * BM1 + mbase];
            float4 av1 = *(const float4*)&As[k * BM1 + mbase + 4];
            float4 bv0 = *(const float4*)&Bs[k * BN1 + nbase];
            float4 bv1 = *(const float4*)&Bs[k * BN1 + nbase + 4];
            float a8[8] = {av0.x, av0.y, av0.z, av0.w, av1.x, av1.y, av1.z, av1.w};
            float b8[8] = {bv0.x, bv0.y, bv0.z, bv0.w, bv1.x, bv1.y, bv1.z, bv1.w};
#pragma unroll
            for (int i = 0; i < 8; i++)
#pragma unroll
                for (int j = 0; j < 8; j++)
                    acc[i][j] = fmaf(a8[i], b8[j], acc[i][j]);
        }
        __syncthreads();
    }

    float bb[8];
#pragma unroll
    for (int j = 0; j < 8; j++) bb[j] = bias[col0 + nbase + j];
#pragma unroll
    for (int i = 0; i < 8; i++) {
        int row = row0 + mbase + i;
        float4* cp = (float4*)&C[(size_t)row * N + col0 + nbase];
        cp[0] = (float4){acc[i][0] + bb[0], acc[i][1] + bb[1],
                         acc[i][2] + bb[2], acc[i][3] + bb[3]};
        cp[1] = (float4){acc[i][4] + bb[4], acc[i][5] + bb[5],
                         acc[i][6] + bb[6], acc[i][7] + bb[7]};
    }
}

// ---------------------------------------------------------------------------
// G2 GEMM, SMEM-A structure: C[m][j] = sum_h s1T[h][m] * W2T[h][j].
// Single-wave 64-thread blocks; block tile 16 rows x 256 cols; lane = 4 cols.
// A (16 rows at fixed k) is WAVE-UNIFORM -> compiler emits s_load_dwordx16;
// per k-step: 1 ds_read_b128 (B) + 1 scalar A-load + 64 v_fmac (SGPR operand
// legal). LDS demand 16 waves x ~12cyc = 192 << 512 VALU cyc/CU -> VALU-bound.
// 16 independent blocks/CU (8KB LDS, launch_bounds(64,4)): no cross-wave
// barriers, staging overlap is statistical across blocks (fixes R7's 63%
// VALUBusy phase-alignment stall).
// NUMERICS CONTRACT: one sequential k-ascending fp32 fmaf chain per output.
// ---------------------------------------------------------------------------
#define G2_BN 256
#define G2_BK 8

__global__ __launch_bounds__(64, 4) void gemm_g2(const float* __restrict__ AT,
                                                 const float* __restrict__ BT,
                                                 float* __restrict__ C) {
    __shared__ __align__(16) float Bs[G2_BK * G2_BN];   // 8 KB

    const int N = HDIM;      // 512
    const int K = HDIM;      // 512
    int lane  = threadIdx.x;             // 0..63
    int row0  = blockIdx.x * 16;         // m-chunk (16 rows)
    int col0  = blockIdx.y * G2_BN;      // n-chunk (256 cols)
    int lane4 = lane * 4;

    float acc[16][4];
#pragma unroll
    for (int i = 0; i < 16; i++)
#pragma unroll
        for (int j = 0; j < 4; j++) acc[i][j] = 0.0f;

    // A ping-pong buffers (wave-uniform -> SGPRs via s_load_dwordx16)
    float a0[16], a1[16];
    {
        const float* p = AT + row0;      // k = 0
#pragma unroll
        for (int i = 0; i < 16; i++) a0[i] = p[i];
    }

    const char* bsrc0 = (const char*)(BT + col0) + lane * 16;
    char* bld = (char*)Bs + lane * 16;

    for (int k0 = 0; k0 < K; k0 += G2_BK) {
        // stage B tile (8 k-rows x 256 cols = 8 KB): one gl2lds per k-row
#pragma unroll
        for (int q = 0; q < G2_BK; q++)
            gl2lds16(bsrc0 + (size_t)(k0 + q) * N * sizeof(float),
                     bld + q * 1024);
        __syncthreads();   // single wave: vmcnt drain + cheap barrier

#pragma unroll
        for (int k = 0; k < G2_BK; k += 2) {
            int kk = k0 + k;
            // prefetch A[kk+1] -> a1
            {
                const float* p = AT + (size_t)(kk + 1) * MROWS + row0;
#pragma unroll
                for (int i = 0; i < 16; i++) a1[i] = p[i];
            }
            {   // compute kk with a0
                float4 bv = *(const float4*)&Bs[k * G2_BN + lane4];
#pragma unroll
                for (int i = 0; i < 16; i++) {
                    acc[i][0] = fmaf(a0[i], bv.x, acc[i][0]);
                    acc[i][1] = fmaf(a0[i], bv.y, acc[i][1]);
                    acc[i][2] = fmaf(a0[i], bv.z, acc[i][2]);
                    acc[i][3] = fmaf(a0[i], bv.w, acc[i][3]);
                }
            }
            // prefetch A[kk+2] -> a0 (clamp keeps last read in-bounds)
            {
                int kn = kk + 2; if (kn > K - 1) kn = K - 1;
                const float* p = AT + (size_t)kn * MROWS + row0;
#pragma unroll
                for (int i = 0; i < 16; i++) a0[i] = p[i];
            }
            {   // compute kk+1 with a1
                float4 bv = *(const float4*)&Bs[(k + 1) * G2_BN + lane4];
#pragma unroll
                for (int i = 0; i < 16; i++) {
                    acc[i][0] = fmaf(a1[i], bv.x, acc[i][0]);
                    acc[i][1] = fmaf(a1[i], bv.y, acc[i][1]);
                    acc[i][2] = fmaf(a1[i], bv.z, acc[i][2]);
                    acc[i][3] = fmaf(a1[i], bv.w, acc[i][3]);
                }
            }
        }
        __syncthreads();   // protect Bs before next staging
    }

    // Epilogue: C normal [m][n]; lanes contiguous 16B -> fully coalesced
#pragma unroll
    for (int i = 0; i < 16; i++) {
        *(float4*)&C[(size_t)(row0 + i) * N + col0 + lane4] =
            (float4){acc[i][0], acc[i][1], acc[i][2], acc[i][3]};
    }
}

// ---------------------------------------------------------------------------
// K2: per-(b,h) LIF scan; reads z1 [m][h] (strided), writes s1T[h][(b,t)]
// CONTIGUOUS (float4 stores) for G2's scalar A-loads. Ping-pong prefetch.
// Arithmetic identical to round 1 (sequential per element).
// ---------------------------------------------------------------------------
__global__ void lif_scan1(const float* __restrict__ z1,
                          float* __restrict__ s1T,
                          const float* __restrict__ th_p) {
    int gtid = blockIdx.x * blockDim.x + threadIdx.x;   // 0..32767
    int b = gtid >> 9;
    int h = gtid & 511;
    float th = *th_p;
    const float* zp = z1 + (size_t)b * TSTEPS * HDIM + h;
    float* sp = s1T + (size_t)h * MROWS + (size_t)b * TSTEPS;   // t-contiguous
    float m = 0.0f;
    float bufA[16], bufB[16];
#pragma unroll
    for (int i = 0; i < 16; i++) bufA[i] = zp[(size_t)i * HDIM];
    for (int t0 = 0; t0 < TSTEPS; t0 += 32) {
#pragma unroll
        for (int i = 0; i < 16; i++) bufB[i] = zp[(size_t)(t0 + 16 + i) * HDIM];
        {
            float ss[16];
#pragma unroll
            for (int i = 0; i < 16; i++) {
                m += bufA[i];
                float thr = m / th - 1.0f;
                ss[i] = (thr >= 0.0f) ? 1.0f : 0.0f;
                if (thr > 0.0f) m -= th;
            }
#pragma unroll
            for (int v = 0; v < 4; v++)
                *(float4*)&sp[t0 + v * 4] =
                    (float4){ss[v * 4], ss[v * 4 + 1], ss[v * 4 + 2], ss[v * 4 + 3]};
        }
        if (t0 + 32 < TSTEPS) {
#pragma unroll
            for (int i = 0; i < 16; i++) bufA[i] = zp[(size_t)(t0 + 32 + i) * HDIM];
        }
        {
            float ss[16];
#pragma unroll
            for (int i = 0; i < 16; i++) {
                m += bufB[i];
                float thr = m / th - 1.0f;
                ss[i] = (thr >= 0.0f) ? 1.0f : 0.0f;
                if (thr > 0.0f) m -= th;
            }
#pragma unroll
            for (int v = 0; v < 4; v++)
                *(float4*)&sp[t0 + 16 + v * 4] =
                    (float4){ss[v * 4], ss[v * 4 + 1], ss[v * 4 + 2], ss[v * 4 + 3]};
        }
    }
}

// ---------------------------------------------------------------------------
// K4: per-(b,j) scan: m2 = (m2 + raw[t]) + bias, spike/reset -> out.
// Ping-pong prefetch (round-7 version, unchanged).
// ---------------------------------------------------------------------------
__global__ void lif_scan2(const float* __restrict__ raw,
                          const float* __restrict__ b2,
                          const float* __restrict__ th_p,
                          float* __restrict__ out) {
    int gtid = blockIdx.x * blockDim.x + threadIdx.x;   // 0..32767
    int b = gtid >> 9;
    int j = gtid & 511;
    float th = *th_p;
    float bias = b2[j];
    const float* rp = raw + (size_t)b * TSTEPS * HDIM + j;
    float* op = out + (size_t)b * TSTEPS * HDIM + j;
    float m = 0.0f;
    float bufA[16], bufB[16];
#pragma unroll
    for (int i = 0; i < 16; i++) bufA[i] = rp[(size_t)i * HDIM];
    for (int t0 = 0; t0 < TSTEPS; t0 += 32) {
#pragma unroll
        for (int i = 0; i < 16; i++) bufB[i] = rp[(size_t)(t0 + 16 + i) * HDIM];
        {
            float ss[16];
#pragma unroll
            for (int i = 0; i < 16; i++) {
                m = (m + bufA[i]) + bias;
                float thr = m / th - 1.0f;
                ss[i] = (thr >= 0.0f) ? 1.0f : 0.0f;
                if (thr > 0.0f) m -= th;
            }
#pragma unroll
            for (int i = 0; i < 16; i++) op[(size_t)(t0 + i) * HDIM] = ss[i];
        }
        if (t0 + 32 < TSTEPS) {
#pragma unroll
            for (int i = 0; i < 16; i++) bufA[i] = rp[(size_t)(t0 + 32 + i) * HDIM];
        }
        {
            float ss[16];
#pragma unroll
            for (int i = 0; i < 16; i++) {
                m = (m + bufB[i]) + bias;
                float thr = m / th - 1.0f;
                ss[i] = (thr >= 0.0f) ? 1.0f : 0.0f;
                if (thr > 0.0f) m -= th;
            }
#pragma unroll
            for (int i = 0; i < 16; i++) op[(size_t)(t0 + 16 + i) * HDIM] = ss[i];
        }
    }
}

// ---------------------------------------------------------------------------
extern "C" void kernel_launch(void* const* d_in, const int* in_sizes, int n_in,
                              void* d_out, int out_size, void* d_ws, size_t ws_size,
                              hipStream_t stream) {
    const float* x    = (const float*)d_in[0];   // (64, 512, 256)
    const float* c1w  = (const float*)d_in[1];   // (512, 256, 3)
    const float* c1b  = (const float*)d_in[2];   // (512,)
    const float* c2w  = (const float*)d_in[3];   // (512, 512, 3)
    const float* c2b  = (const float*)d_in[4];   // (512,)
    const float* th1  = (const float*)d_in[5];   // scalar
    const float* th2  = (const float*)d_in[6];   // scalar
    float* out = (float*)d_out;                  // (64, 512, 512)

    // Workspace layout (floats):
    //   W1T : 131072   (512 KB)   [k=i][n=h]
    //   W2T : 262144   (1 MB)     [k=h][n=j]
    //   bufA: 16777216 (64 MB)    z1, later m2raw   [m][n]
    //   bufS: 16777216 (64 MB)    s1T               [h][(b,t)]
    float* W1T  = (float*)d_ws;
    float* W2T  = W1T + IDIM * HDIM;
    float* bufA = W2T + HDIM * HDIM;
    float* bufS = bufA + (size_t)MROWS * HDIM;

    // K0: weight extraction
    extract_weights<<<(HDIM * HDIM + 255) / 256, 256, 0, stream>>>(c1w, c2w, W1T, W2T);

    // K1: z1 = x @ W1T + b1   (M=32768, K=256, N=512) -> bufA
    {
        dim3 grid(MROWS / BM1, HDIM / BN1);
        gemm_g1<<<grid, 256, 0, stream>>>(x, W1T, c1b, bufA, IDIM);
    }

    // K2: s1 scan -> bufS (transposed s1T[h][(b,t)])
    lif_scan1<<<MROWS / 64, 64, 0, stream>>>(bufA, bufS, th1);

    // K3: m2raw = s1 @ W2T   (M=32768, K=512, N=512) -> bufA (SMEM-A GEMM)
    {
        dim3 grid(MROWS / 16, HDIM / G2_BN);
        gemm_g2<<<grid, 64, 0, stream>>>(bufS, W2T, bufA);
    }

    // K4: s2 scan -> out
    lif_scan2<<<MROWS / 64, 64, 0, stream>>>(bufA, c2b, th2, out);
}